// Round 8
// baseline (474.268 us; speedup 1.0000x reference)
//
#include <hip/hip_runtime.h>
#include <hip/hip_bf16.h>

#define N 8192
#define IN_F 512
#define OUT_F 64
#define S_SPLIT 16
#define JT (N / S_SPLIT)   // 512 columns per split
#define NB (N / 8)         // 1024 mask bytes per row
#define LDP 536            // LDS row pitch in shorts: stride 268 dw ≡ 12 (mod 32)
                           // -> <=2-way bank aliasing on b128 reads (free, m136)
#define WHB 128            // wh blocks at the FRONT of the fused grid
#define PACKB ((N / 32) * (N / 256) * 4)   // 32768 pack blocks
#define LOG2E 1.44269504088896340736f

typedef __attribute__((ext_vector_type(8))) short short8;
typedef __attribute__((ext_vector_type(4))) float floatx4;
typedef __attribute__((ext_vector_type(4))) int intx4;

__device__ inline short f2bf(float x) {
    __hip_bfloat16 b = __float2bfloat16(x);
    return __builtin_bit_cast(short, b);
}

__device__ inline float fexp2(float x) {
#if __has_builtin(__builtin_amdgcn_exp2f)
    return __builtin_amdgcn_exp2f(x);
#else
    return exp2f(x);
#endif
}

// K0: W [512][64] fp32 -> WT [64][512] bf16 (tiny, runs first).
// Also zeroes the split-K semaphore array (workspace is poisoned every
// iteration; stream order guarantees visibility before k_attn).
__global__ void k_wt(const float* __restrict__ W, short* __restrict__ WT,
                     int* __restrict__ cnt) {
    int idx = blockIdx.x * 256 + threadIdx.x;    // 32768 total
    int k = idx >> 6, f = idx & 63;
    WT[f * IN_F + k] = f2bf(W[k * OUT_F + f]);
    if (blockIdx.x == 0 && threadIdx.x < 32) cnt[threadIdx.x] = 0;
}

// K1: FUSED pack + wh (proven R4: pack is pure HBM streaming, wh is
// latency-bound MFMA -- independent, one dispatch overlaps them; wh blocks
// dispatched first so they hide under the pack stream). EXACT R4 version.
__global__ __launch_bounds__(256) void k_packwh(const int* __restrict__ adj,
                                                unsigned* __restrict__ mask,
                                                const float* __restrict__ h,
                                                const short* __restrict__ WT,
                                                const float* __restrict__ a,
                                                short* __restrict__ WHbT,
                                                float* __restrict__ wh1,
                                                float* __restrict__ wh2) {
    __shared__ float tileS[4][OUT_F][17];
    int tid = threadIdx.x;

    if (blockIdx.x >= WHB) {
        // ---- pack: adjacency int32 {0,1} -> bitmask via ballot. Wave handles
        // 512 consecutive flat elements: 8 coalesced dword loads, 8 ballots,
        // lanes 0..15 store the 64B result.
        int bid = blockIdx.x - WHB;
        int wv = (bid * 256 + tid) >> 6;          // global wave id
        int lane = tid & 63;
        const int* p = adj + (size_t)wv * 512 + lane;
        unsigned long long m0 = __ballot(p[0]   > 0);
        unsigned long long m1 = __ballot(p[64]  > 0);
        unsigned long long m2 = __ballot(p[128] > 0);
        unsigned long long m3 = __ballot(p[192] > 0);
        unsigned long long m4 = __ballot(p[256] > 0);
        unsigned long long m5 = __ballot(p[320] > 0);
        unsigned long long m6 = __ballot(p[384] > 0);
        unsigned long long m7 = __ballot(p[448] > 0);
        if (lane < 16) {
            unsigned long long s0 = (lane & 2) ? m1 : m0;
            unsigned long long s1 = (lane & 2) ? m3 : m2;
            unsigned long long s2 = (lane & 2) ? m5 : m4;
            unsigned long long s3 = (lane & 2) ? m7 : m6;
            unsigned long long t0 = (lane & 4) ? s1 : s0;
            unsigned long long t1 = (lane & 4) ? s3 : s2;
            unsigned long long u  = (lane & 8) ? t1 : t0;
            unsigned dw = (lane & 1) ? (unsigned)(u >> 32) : (unsigned)u;
            mask[wv * 16 + lane] = dw;
        }
        return;
    }

    // ---- wh: WH = h @ W via bf16 MFMA. 4 waves/block, 16 rows each.
    // Epilogue: WHbT bf16 [64][8192] transpose + wh1/wh2 PRE-SCALED by log2e.
    int w = tid >> 6, lane = tid & 63;
    int n = lane & 15, q = lane >> 4;
    int i0 = (blockIdx.x * 4 + w) * 16;
    float (*tile)[17] = tileS[w];
    const float* hp = h + (size_t)(i0 + n) * IN_F + q * 8;
    floatx4 acc[4] = {};
#pragma unroll
    for (int k0 = 0; k0 < IN_F; k0 += 32) {
        floatx4 h0 = *(const floatx4*)(hp + k0);
        floatx4 h1 = *(const floatx4*)(hp + k0 + 4);
        short8 af;
#pragma unroll
        for (int j = 0; j < 4; j++) { af[j] = f2bf(h0[j]); af[j + 4] = f2bf(h1[j]); }
#pragma unroll
        for (int b = 0; b < 4; b++) {
            short8 bf_ = *(const short8*)(WT + (b * 16 + n) * IN_F + k0 + q * 8);
            acc[b] = __builtin_amdgcn_mfma_f32_16x16x32_bf16(af, bf_, acc[b], 0, 0, 0);
        }
    }
#pragma unroll
    for (int b = 0; b < 4; b++)
#pragma unroll
        for (int r = 0; r < 4; r++)
            tile[b * 16 + n][q * 4 + r] = acc[b][r];
    float a1v[4], a2v[4];
#pragma unroll
    for (int b = 0; b < 4; b++) { a1v[b] = a[b * 16 + n]; a2v[b] = a[OUT_F + b * 16 + n]; }
#pragma unroll
    for (int r = 0; r < 4; r++) {
        float s1 = 0.f, s2 = 0.f;
#pragma unroll
        for (int b = 0; b < 4; b++) { s1 += acc[b][r] * a1v[b]; s2 += acc[b][r] * a2v[b]; }
#pragma unroll
        for (int m = 1; m <= 8; m <<= 1) {
            s1 += __shfl_xor(s1, m, 64);
            s2 += __shfl_xor(s2, m, 64);
        }
        if (n == 0) {
            wh1[i0 + q * 4 + r] = s1 * LOG2E;
            wh2[i0 + q * 4 + r] = s2 * LOG2E;
        }
    }
    __syncthreads();
    const float* tc = tile[lane & 63];
    short8 s0, s1v;
#pragma unroll
    for (int k = 0; k < 8; k++) { s0[k] = f2bf(tc[k]); s1v[k] = f2bf(tc[k + 8]); }
    *(short8*)(WHbT + (size_t)lane * N + i0) = s0;
    *(short8*)(WHbT + (size_t)lane * N + i0 + 8) = s1v;
}

// K2: mask-based attention -- EXACT R4 structure (proven best) + fused
// split-K finalization: after writing partials, release-fence + bump
// cnt[bx]; the LAST of the 16 split-blocks for a row band acquires and
// reduces that band (num/den sum -> div -> ELU -> out). Removes the
// separate k_final dispatch; reduction overlaps other bands' compute.
__global__ __launch_bounds__(256, 2) void k_attn(const unsigned char* __restrict__ mask,
                                                 const short* __restrict__ WHbT,
                                                 const float* __restrict__ wh1,
                                                 const float* __restrict__ wh2,
                                                 float* __restrict__ num_part,
                                                 float* __restrict__ den_part,
                                                 int* __restrict__ cnt,
                                                 float* __restrict__ out) {
    __shared__ short ldsb[OUT_F * LDP];          // 67 KB -> 2 blocks/CU
    __shared__ int lastf;
    int tid = threadIdx.x;
    int w = tid >> 6;
    int lane = tid & 63;
    int n = lane & 15, q = lane >> 4;
    int split = blockIdx.y;
    int j0 = split * JT;
    int i0 = blockIdx.x * 256 + w * 64;          // wave's first row

    // stage B-tile once: each wave reads one full WHbT row (1KB) per iteration
#pragma unroll
    for (int l = 0; l < 16; l++) {
        int idx = l * 256 + tid;
        int f = idx >> 6, c16 = idx & 63;
        short8 v = *(const short8*)(WHbT + (size_t)f * N + j0 + c16 * 8);
        *(short8*)(ldsb + f * LDP + c16 * 8) = v;
    }
    __syncthreads();

    float wh1f[4];
#pragma unroll
    for (int rf = 0; rf < 4; rf++) wh1f[rf] = wh1[i0 + rf * 16 + n];

    floatx4 acc[4][4] = {};                       // [rf][b]
    floatx4 accd[4] = {};                         // den accumulators (col 0)
    const float* w2p = wh2 + j0 + q * 8;
    const short* lp = ldsb + q * 8;
    int qs = q * 8;

    // ones B-fragment: B[k][col] = 1 iff col==0 -> D[:,0] = row-sum of A
    short8 onesf = {};
    if (n == 0) {
        short o = f2bf(1.0f);
#pragma unroll
        for (int jj = 0; jj < 8; jj++) onesf[jj] = o;
    }

    // mask double-buffer across g-groups (distance = 4 steps, ample for L2/L3)
    intx4 mcur[4], mnxt[4];
#pragma unroll
    for (int rf = 0; rf < 4; rf++)
        mcur[rf] = *(const intx4*)(mask + (size_t)(i0 + rf * 16 + n) * NB + split * 64);

    for (int g = 0; g < 4; g++) {
        if (g < 3) {
#pragma unroll
            for (int rf = 0; rf < 4; rf++)
                mnxt[rf] = *(const intx4*)(mask + (size_t)(i0 + rf * 16 + n) * NB
                                           + split * 64 + (g + 1) * 16);
        }
#pragma unroll
        for (int d = 0; d < 4; d++) {
            int s = g * 4 + d;
            floatx4 w20 = *(const floatx4*)(w2p + s * 32);
            floatx4 w21 = *(const floatx4*)(w2p + s * 32 + 4);
            short8 bfr[4];
#pragma unroll
            for (int b = 0; b < 4; b++)
                bfr[b] = *(const short8*)(lp + (b * 16 + n) * LDP + s * 32);
#pragma unroll
            for (int rf = 0; rf < 4; rf++) {
                unsigned md = (unsigned)mcur[rf][d] >> qs;
                float p[8];
#pragma unroll
                for (int jj = 0; jj < 8; jj++) {
                    // wh1/wh2 pre-scaled by log2e: exp(leaky(e)) == exp2(max(e*,.01e*))
                    float e = wh1f[rf] + ((jj < 4) ? w20[jj] : w21[jj - 4]);
                    float el = fmaxf(e, 0.01f * e);
                    el = ((md >> jj) & 1u) ? el : -1024.0f;  // exp2(-1024)==0, exact
                    p[jj] = fexp2(el);
                }
                short8 af;
#pragma unroll
                for (int jj = 0; jj < 8; jj++) af[jj] = f2bf(p[jj]);
#pragma unroll
                for (int b = 0; b < 4; b++)
                    acc[rf][b] = __builtin_amdgcn_mfma_f32_16x16x32_bf16(af, bfr[b], acc[rf][b], 0, 0, 0);
                accd[rf] = __builtin_amdgcn_mfma_f32_16x16x32_bf16(af, onesf, accd[rf], 0, 0, 0);
            }
        }
#pragma unroll
        for (int rf = 0; rf < 4; rf++) mcur[rf] = mnxt[rf];
    }

    // den: C/D layout col = lane&15, row = q*4+r -> lanes n==0 hold all 16 rows
#pragma unroll
    for (int rf = 0; rf < 4; rf++)
        if (n == 0)
            *(floatx4*)(den_part + (size_t)split * N + i0 + rf * 16 + q * 4) = accd[rf];

    float* np_ = num_part + (size_t)split * N * OUT_F;
#pragma unroll
    for (int rf = 0; rf < 4; rf++)
#pragma unroll
        for (int b = 0; b < 4; b++)
#pragma unroll
            for (int r = 0; r < 4; r++)
                np_[(size_t)(i0 + rf * 16 + q * 4 + r) * OUT_F + b * 16 + n] = acc[rf][b][r];

    // ---- split-K finalization: last block of the 16 splits for this band
    // reduces rows [bx*256, bx*256+256). Release: threadfence + ACQ_REL atomic.
    __threadfence();
    if (tid == 0) {
        int old = __hip_atomic_fetch_add(&cnt[blockIdx.x], 1,
                                         __ATOMIC_ACQ_REL, __HIP_MEMORY_SCOPE_AGENT);
        lastf = (old == S_SPLIT - 1);
    }
    __syncthreads();
    if (lastf) {
        __threadfence();                          // acquire side
        size_t base = (size_t)blockIdx.x * 256 * OUT_F;   // band start (floats)
#pragma unroll
        for (int it = 0; it < 16; it++) {
            size_t idx = base + (size_t)(it * 256 + tid) * 4;  // floatx4-aligned
            int row = (int)(idx >> 6);
            floatx4 s = {};
            float dsum = 0.f;
#pragma unroll
            for (int sp = 0; sp < S_SPLIT; sp++) {
                s += *(const floatx4*)(num_part + (size_t)sp * N * OUT_F + idx);
                dsum += den_part[sp * N + row];
            }
            floatx4 o;
#pragma unroll
            for (int j = 0; j < 4; j++) {
                float x = s[j] / dsum;
                o[j] = (x > 0.f) ? x : (__expf(x) - 1.f);
            }
            *(floatx4*)(out + idx) = o;
        }
    }
}

extern "C" void kernel_launch(void* const* d_in, const int* in_sizes, int n_in,
                              void* d_out, int out_size, void* d_ws, size_t ws_size,
                              hipStream_t stream) {
    const float* h = (const float*)d_in[0];
    const int* adj = (const int*)d_in[1];
    const float* W = (const float*)d_in[2];
    const float* a = (const float*)d_in[3];
    float* out = (float*)d_out;

    char* ws = (char*)d_ws;
    short* WHbT     = (short*)(ws);                                  // 1 MB
    short* WT       = (short*)(ws + (size_t)(1 << 20));              // 64 KB
    float* wh1      = (float*)(ws + (size_t)(1 << 20) + (64 << 10)); // 32 KB
    float* wh2      = wh1 + N;                                       // 32 KB
    unsigned* maskb = (unsigned*)(ws + (size_t)(2 << 20));           // 8 MB
    float* num_p    = (float*)(ws + (size_t)(16 << 20));             // 32 MB
    float* den_p    = (float*)(ws + (size_t)(48 << 20));             // 512 KB
    int*   cnt      = (int*)(ws + (size_t)(49 << 20));               // 128 B

    k_wt<<<dim3(128), dim3(256), 0, stream>>>(W, WT, cnt);
    k_packwh<<<dim3(WHB + PACKB), dim3(256), 0, stream>>>(adj, maskb, h, WT, a,
                                                          WHbT, wh1, wh2);
    k_attn<<<dim3(N / 256, S_SPLIT), dim3(256), 0, stream>>>((const unsigned char*)maskb,
                                                             WHbT, wh1, wh2, num_p, den_p,
                                                             cnt, out);
}

// Round 9
// 397.744 us; speedup vs baseline: 1.1924x; 1.1924x over previous
//
#include <hip/hip_runtime.h>
#include <hip/hip_bf16.h>

#define N 8192
#define IN_F 512
#define OUT_F 64
#define S_SPLIT 16
#define JT (N / S_SPLIT)   // 512 columns per split
#define NB (N / 8)         // 1024 mask bytes per row
#define LDP 536            // LDS row pitch in shorts: stride 268 dw ≡ 12 (mod 32)
                           // -> <=2-way bank aliasing on b128 reads (free, m136)
#define WHB 128            // wh blocks at the FRONT of the fused grid
#define PACKB ((N / 32) * (N / 256) * 4)   // 32768 pack blocks
#define LOG2E 1.44269504088896340736f

typedef __attribute__((ext_vector_type(8))) short short8;
typedef __attribute__((ext_vector_type(4))) float floatx4;
typedef __attribute__((ext_vector_type(4))) int intx4;

__device__ inline short f2bf(float x) {
    __hip_bfloat16 b = __float2bfloat16(x);
    return __builtin_bit_cast(short, b);
}

__device__ inline float fexp2(float x) {
#if __has_builtin(__builtin_amdgcn_exp2f)
    return __builtin_amdgcn_exp2f(x);
#else
    return exp2f(x);
#endif
}

// K0: W [512][64] fp32 -> WT [64][512] bf16 (tiny, runs first)
__global__ void k_wt(const float* __restrict__ W, short* __restrict__ WT) {
    int idx = blockIdx.x * 256 + threadIdx.x;    // 32768 total
    int k = idx >> 6, f = idx & 63;
    WT[f * IN_F + k] = f2bf(W[k * OUT_F + f]);
}

// K1: FUSED pack + wh (proven round 4: pack is pure HBM streaming, wh is
// latency-bound MFMA -- independent, one dispatch overlaps them; wh blocks
// dispatched first so they hide under the pack stream).
__global__ __launch_bounds__(256) void k_packwh(const int* __restrict__ adj,
                                                unsigned* __restrict__ mask,
                                                const float* __restrict__ h,
                                                const short* __restrict__ WT,
                                                const float* __restrict__ a,
                                                short* __restrict__ WHbT,
                                                float* __restrict__ wh1,
                                                float* __restrict__ wh2) {
    __shared__ float tileS[4][OUT_F][17];
    int tid = threadIdx.x;

    if (blockIdx.x >= WHB) {
        // ---- pack: adjacency int32 {0,1} -> bitmask via ballot. Wave handles
        // 512 consecutive flat elements: 8 coalesced dword loads, 8 ballots,
        // lanes 0..15 store the 64B result.
        int bid = blockIdx.x - WHB;
        int wv = (bid * 256 + tid) >> 6;          // global wave id
        int lane = tid & 63;
        const int* p = adj + (size_t)wv * 512 + lane;
        unsigned long long m0 = __ballot(p[0]   > 0);
        unsigned long long m1 = __ballot(p[64]  > 0);
        unsigned long long m2 = __ballot(p[128] > 0);
        unsigned long long m3 = __ballot(p[192] > 0);
        unsigned long long m4 = __ballot(p[256] > 0);
        unsigned long long m5 = __ballot(p[320] > 0);
        unsigned long long m6 = __ballot(p[384] > 0);
        unsigned long long m7 = __ballot(p[448] > 0);
        if (lane < 16) {
            unsigned long long s0 = (lane & 2) ? m1 : m0;
            unsigned long long s1 = (lane & 2) ? m3 : m2;
            unsigned long long s2 = (lane & 2) ? m5 : m4;
            unsigned long long s3 = (lane & 2) ? m7 : m6;
            unsigned long long t0 = (lane & 4) ? s1 : s0;
            unsigned long long t1 = (lane & 4) ? s3 : s2;
            unsigned long long u  = (lane & 8) ? t1 : t0;
            unsigned dw = (lane & 1) ? (unsigned)(u >> 32) : (unsigned)u;
            mask[wv * 16 + lane] = dw;
        }
        return;
    }

    // ---- wh: WH = h @ W via bf16 MFMA. 4 waves/block, 16 rows each.
    // Epilogue: WHbT bf16 [64][8192] transpose + wh1/wh2 PRE-SCALED by log2e.
    int w = tid >> 6, lane = tid & 63;
    int n = lane & 15, q = lane >> 4;
    int i0 = (blockIdx.x * 4 + w) * 16;
    float (*tile)[17] = tileS[w];
    const float* hp = h + (size_t)(i0 + n) * IN_F + q * 8;
    floatx4 acc[4] = {};
#pragma unroll
    for (int k0 = 0; k0 < IN_F; k0 += 32) {
        floatx4 h0 = *(const floatx4*)(hp + k0);
        floatx4 h1 = *(const floatx4*)(hp + k0 + 4);
        short8 af;
#pragma unroll
        for (int j = 0; j < 4; j++) { af[j] = f2bf(h0[j]); af[j + 4] = f2bf(h1[j]); }
#pragma unroll
        for (int b = 0; b < 4; b++) {
            short8 bf_ = *(const short8*)(WT + (b * 16 + n) * IN_F + k0 + q * 8);
            acc[b] = __builtin_amdgcn_mfma_f32_16x16x32_bf16(af, bf_, acc[b], 0, 0, 0);
        }
    }
#pragma unroll
    for (int b = 0; b < 4; b++)
#pragma unroll
        for (int r = 0; r < 4; r++)
            tile[b * 16 + n][q * 4 + r] = acc[b][r];
    float a1v[4], a2v[4];
#pragma unroll
    for (int b = 0; b < 4; b++) { a1v[b] = a[b * 16 + n]; a2v[b] = a[OUT_F + b * 16 + n]; }
#pragma unroll
    for (int r = 0; r < 4; r++) {
        float s1 = 0.f, s2 = 0.f;
#pragma unroll
        for (int b = 0; b < 4; b++) { s1 += acc[b][r] * a1v[b]; s2 += acc[b][r] * a2v[b]; }
#pragma unroll
        for (int m = 1; m <= 8; m <<= 1) {
            s1 += __shfl_xor(s1, m, 64);
            s2 += __shfl_xor(s2, m, 64);
        }
        if (n == 0) {
            wh1[i0 + q * 4 + r] = s1 * LOG2E;
            wh2[i0 + q * 4 + r] = s2 * LOG2E;
        }
    }
    __syncthreads();
    const float* tc = tile[lane & 63];
    short8 s0, s1v;
#pragma unroll
    for (int k = 0; k < 8; k++) { s0[k] = f2bf(tc[k]); s1v[k] = f2bf(tc[k + 8]); }
    *(short8*)(WHbT + (size_t)lane * N + i0) = s0;
    *(short8*)(WHbT + (size_t)lane * N + i0 + 8) = s1v;
}

// K2: mask-based attention: leaky_relu + exp2 + (P @ [WH | 1]) partials.
// EXACT R4 structure -- proven best across R5 (no-LDS), R6 (half-LDS),
// R8 (fused split-K final), all of which regressed. 67 KB LDS tile staged
// once, 2 barriers, launch_bounds(256,2), wave owns 64 rows, 16 steps.
// exp2 w/ prefolded log2e, mask-select before exp, ones-column MFMA den.
__global__ __launch_bounds__(256, 2) void k_attn(const unsigned char* __restrict__ mask,
                                                 const short* __restrict__ WHbT,
                                                 const float* __restrict__ wh1,
                                                 const float* __restrict__ wh2,
                                                 float* __restrict__ num_part,
                                                 float* __restrict__ den_part) {
    __shared__ short ldsb[OUT_F * LDP];          // 67 KB -> 2 blocks/CU
    int tid = threadIdx.x;
    int w = tid >> 6;
    int lane = tid & 63;
    int n = lane & 15, q = lane >> 4;
    int split = blockIdx.y;
    int j0 = split * JT;
    int i0 = blockIdx.x * 256 + w * 64;          // wave's first row

    // stage B-tile once: each wave reads one full WHbT row (1KB) per iteration
#pragma unroll
    for (int l = 0; l < 16; l++) {
        int idx = l * 256 + tid;
        int f = idx >> 6, c16 = idx & 63;
        short8 v = *(const short8*)(WHbT + (size_t)f * N + j0 + c16 * 8);
        *(short8*)(ldsb + f * LDP + c16 * 8) = v;
    }
    __syncthreads();

    float wh1f[4];
#pragma unroll
    for (int rf = 0; rf < 4; rf++) wh1f[rf] = wh1[i0 + rf * 16 + n];

    floatx4 acc[4][4] = {};                       // [rf][b]
    floatx4 accd[4] = {};                         // den accumulators (col 0)
    const float* w2p = wh2 + j0 + q * 8;
    const short* lp = ldsb + q * 8;
    int qs = q * 8;

    // ones B-fragment: B[k][col] = 1 iff col==0 -> D[:,0] = row-sum of A
    short8 onesf = {};
    if (n == 0) {
        short o = f2bf(1.0f);
#pragma unroll
        for (int jj = 0; jj < 8; jj++) onesf[jj] = o;
    }

    // mask double-buffer across g-groups (distance = 4 steps, ample for L2/L3)
    intx4 mcur[4], mnxt[4];
#pragma unroll
    for (int rf = 0; rf < 4; rf++)
        mcur[rf] = *(const intx4*)(mask + (size_t)(i0 + rf * 16 + n) * NB + split * 64);

    for (int g = 0; g < 4; g++) {
        if (g < 3) {
#pragma unroll
            for (int rf = 0; rf < 4; rf++)
                mnxt[rf] = *(const intx4*)(mask + (size_t)(i0 + rf * 16 + n) * NB
                                           + split * 64 + (g + 1) * 16);
        }
#pragma unroll
        for (int d = 0; d < 4; d++) {
            int s = g * 4 + d;
            floatx4 w20 = *(const floatx4*)(w2p + s * 32);
            floatx4 w21 = *(const floatx4*)(w2p + s * 32 + 4);
            short8 bfr[4];
#pragma unroll
            for (int b = 0; b < 4; b++)
                bfr[b] = *(const short8*)(lp + (b * 16 + n) * LDP + s * 32);
#pragma unroll
            for (int rf = 0; rf < 4; rf++) {
                unsigned md = (unsigned)mcur[rf][d] >> qs;
                float p[8];
#pragma unroll
                for (int jj = 0; jj < 8; jj++) {
                    // wh1/wh2 pre-scaled by log2e: exp(leaky(e)) == exp2(max(e*,.01e*))
                    float e = wh1f[rf] + ((jj < 4) ? w20[jj] : w21[jj - 4]);
                    float el = fmaxf(e, 0.01f * e);
                    el = ((md >> jj) & 1u) ? el : -1024.0f;  // exp2(-1024)==0, exact
                    p[jj] = fexp2(el);
                }
                short8 af;
#pragma unroll
                for (int jj = 0; jj < 8; jj++) af[jj] = f2bf(p[jj]);
#pragma unroll
                for (int b = 0; b < 4; b++)
                    acc[rf][b] = __builtin_amdgcn_mfma_f32_16x16x32_bf16(af, bfr[b], acc[rf][b], 0, 0, 0);
                accd[rf] = __builtin_amdgcn_mfma_f32_16x16x32_bf16(af, onesf, accd[rf], 0, 0, 0);
            }
        }
#pragma unroll
        for (int rf = 0; rf < 4; rf++) mcur[rf] = mnxt[rf];
    }

    // den: C/D layout col = lane&15, row = q*4+r -> lanes n==0 hold all 16 rows
#pragma unroll
    for (int rf = 0; rf < 4; rf++)
        if (n == 0)
            *(floatx4*)(den_part + (size_t)split * N + i0 + rf * 16 + q * 4) = accd[rf];

    float* np_ = num_part + (size_t)split * N * OUT_F;
#pragma unroll
    for (int rf = 0; rf < 4; rf++)
#pragma unroll
        for (int b = 0; b < 4; b++)
#pragma unroll
            for (int r = 0; r < 4; r++)
                np_[(size_t)(i0 + rf * 16 + q * 4 + r) * OUT_F + b * 16 + n] = acc[rf][b][r];
}

// K3: out = elu( (Σ num_part) / (Σ den_part) )
__global__ void k_final(const float* __restrict__ num_part,
                        const float* __restrict__ den_part,
                        float* __restrict__ out) {
    int idx = blockIdx.x * 256 + threadIdx.x;    // 524288 total
    int row = idx >> 6;
    float s = 0.f, d = 0.f;
#pragma unroll
    for (int sp = 0; sp < S_SPLIT; sp++) {
        s += num_part[(size_t)sp * N * OUT_F + idx];
        d += den_part[sp * N + row];
    }
    float x = s / d;
    out[idx] = (x > 0.f) ? x : (__expf(x) - 1.f);
}

extern "C" void kernel_launch(void* const* d_in, const int* in_sizes, int n_in,
                              void* d_out, int out_size, void* d_ws, size_t ws_size,
                              hipStream_t stream) {
    const float* h = (const float*)d_in[0];
    const int* adj = (const int*)d_in[1];
    const float* W = (const float*)d_in[2];
    const float* a = (const float*)d_in[3];
    float* out = (float*)d_out;

    char* ws = (char*)d_ws;
    short* WHbT     = (short*)(ws);                                  // 1 MB
    short* WT       = (short*)(ws + (size_t)(1 << 20));              // 64 KB
    float* wh1      = (float*)(ws + (size_t)(1 << 20) + (64 << 10)); // 32 KB
    float* wh2      = wh1 + N;                                       // 32 KB
    unsigned* maskb = (unsigned*)(ws + (size_t)(2 << 20));           // 8 MB
    float* num_p    = (float*)(ws + (size_t)(16 << 20));             // 32 MB
    float* den_p    = (float*)(ws + (size_t)(48 << 20));             // 512 KB

    k_wt<<<dim3(128), dim3(256), 0, stream>>>(W, WT);
    k_packwh<<<dim3(WHB + PACKB), dim3(256), 0, stream>>>(adj, maskb, h, WT, a,
                                                          WHbT, wh1, wh2);
    k_attn<<<dim3(N / 256, S_SPLIT), dim3(256), 0, stream>>>((const unsigned char*)maskb,
                                                             WHbT, wh1, wh2, num_p, den_p);
    k_final<<<dim3((N * OUT_F) / 256), dim3(256), 0, stream>>>(num_p, den_p, out);
}